// Round 8
// baseline (172.634 us; speedup 1.0000x reference)
//
#include <hip/hip_runtime.h>

#define BLK 256
#define ANCH 256

constexpr float LN2 = 0.6931471805599453f;

// Background focal partial for one float4:  sum_i p_i^2 * log2(1 - p_i)   (<= 0)
__device__ __forceinline__ float bg4(const float4 v) {
    const float pv[4] = { v.x, v.y, v.z, v.w };
    float acc = 0.0f;
#pragma unroll
    for (int i = 0; i < 4; ++i) {
        const float p = fminf(fmaxf(pv[i], 0.0001f), 1.0f - 0.0001f);
        acc = fmaf(p * p, __log2f(1.0f - p), acc);
    }
    return acc;
}

// One quad (4 consecutive classes c0..c0+3) of one anchor with status st.
// st: 0..K-1 = positive label, 254 = negative, 255 = ignore.
__device__ __forceinline__ void quad(const float4 v, const int st, const int c0,
                                     float& cls_part) {
    const float s = bg4(v);
    cls_part = fmaf(s, (st == 255) ? 0.0f : -0.75f * LN2, cls_part);
    const unsigned d = (unsigned)(st - c0);
    if (d < 4u) {                       // rare: this quad holds the positive class
        float p = v.x;
        p = (d == 1) ? v.y : p;
        p = (d == 2) ? v.z : p;
        p = (d == 3) ? v.w : p;
        p = fminf(fmaxf(p, 0.0001f), 1.0f - 0.0001f);
        const float bg = p * p * __log2f(1.0f - p);
        const float q  = 1.0f - p;
        const float fg = q * q * __log2f(p);
        cls_part += -LN2 * (0.25f * fg - 0.75f * bg);   // add fg-term, remove bg-term
    }
}

template <int KQ_C, int M_C>
__global__ __launch_bounds__(BLK) void focal_main(
    const float* __restrict__ cls,
    const float* __restrict__ loc,
    const float* __restrict__ anchors,
    const float* __restrict__ anno,
    int A, int kq_dyn, int m_dyn, int B, int NBX,
    float* __restrict__ part,          // [3][B][NBX] partials, no data atomics
    unsigned int* __restrict__ counter, // zeroed by memsetAsync each call
    float* __restrict__ out)
{
    const int KQ = KQ_C ? KQ_C : kq_dyn;
    const int M  = M_C  ? M_C  : m_dyn;
    const int b  = blockIdx.y;
    const int bx = blockIdx.x;
    const int a0 = bx * ANCH;
    const int t  = threadIdx.x;
    const int nA = min(ANCH, A - a0);

    __shared__ float4 s_box[64];
    __shared__ float  s_area[64];      // NaN => invalid box (never selected)
    __shared__ float  s_lab[64];
    __shared__ int    s_status[ANCH];
    __shared__ float  s_redc[BLK / 64];
    __shared__ float  s_redl[BLK / 64];
    __shared__ float  s_redp[BLK / 64];
    __shared__ int    s_islast;

    const float4* __restrict__ cls4 =
        reinterpret_cast<const float4*>(cls) + ((size_t)b * A + a0) * KQ;
    const bool full = (KQ_C == 20) && (nA == ANCH);

    // ---- stage annotations BEFORE issuing bulk loads (barrier drains little)
    if (t < M) {
        const float* ap = anno + ((size_t)b * M + t) * 5;
        const float x1 = ap[0], y1 = ap[1], x2 = ap[2], y2 = ap[3], lb = ap[4];
        s_box[t]  = make_float4(x1, y1, x2, y2);
        s_area[t] = (lb != -1.0f) ? (x2 - x1) * (y2 - y1)
                                  : __int_as_float(0x7fc00000);  // NaN
        s_lab[t]  = lb;
    }
    __syncthreads();

#define LOADB(R, BK)                                                        \
    do {                                                                    \
        _Pragma("unroll") for (int u_ = 0; u_ < 4; ++u_)                    \
            R[u_] = cls4[t + ((BK) * 4 + u_) * BLK];                        \
    } while (0)

#define EVALB(R, BK)                                                        \
    do {                                                                    \
        _Pragma("unroll") for (int u_ = 0; u_ < 4; ++u_) {                  \
            const int idx_ = t + ((BK) * 4 + u_) * BLK;                     \
            const int al_  = idx_ / 20;                                     \
            const int c0_  = (idx_ - al_ * 20) * 4;                         \
            quad(R[u_], s_status[al_], c0_, cls_part);                      \
        }                                                                   \
    } while (0)

    // ---- 8 cls preloads in flight; phase-1 compute overlaps them ----
    float4 va[4], vb[4];
    if (full) { LOADB(va, 0); LOADB(vb, 1); }

    float loc_part = 0.0f;
    float pos_part = 0.0f;

    // ---- Phase 1: per-anchor status + loc loss; division-free argmax ----
    if (t < nA) {
        const int a = a0 + t;
        const float4 anc = reinterpret_cast<const float4*>(anchors)[a];
        const float ax1 = anc.x, ay1 = anc.y, ax2 = anc.z, ay2 = anc.w;
        const float area_a = (ax2 - ax1) * (ay2 - ay1);

        // best IoU tracked as ratio bi/bu; invalid boxes have NaN area ->
        // NaN uni -> compare false -> never selected. init (-2,1) < -1.
        float bi = -2.0f, bu = 1.0f;
        int arg = 0;
#pragma unroll
        for (int m = 0; m < M; ++m) {
            const float4 bb = s_box[m];
            const float ab  = s_area[m];
            const float iw = fmaxf(fminf(ax2, bb.z) - fmaxf(ax1, bb.x), 0.0f);
            const float ih = fmaxf(fminf(ay2, bb.w) - fmaxf(ay1, bb.y), 0.0f);
            const float inter = iw * ih;
            const float uni = fmaxf(area_a + ab - inter, 1e-8f);
            const bool better = inter * bu > bi * uni;   // strict > = first-max
            bi  = better ? inter : bi;
            bu  = better ? uni   : bu;
            arg = better ? m     : arg;
        }

        const bool pos = bi >= 0.5f * bu;
        const bool neg = bi <  0.4f * bu;
        s_status[t] = pos ? (int)s_lab[arg] : (neg ? 254 : 255);

        if (pos) {
            pos_part = 1.0f;
            const float4 g = s_box[arg];
            const float aw = ax2 - ax1, ah = ay2 - ay1;
            const float acx = ax1 + 0.5f * aw, acy = ay1 + 0.5f * ah;
            const float gwr = g.z - g.x, ghr = g.w - g.y;
            const float gcx = g.x + 0.5f * gwr, gcy = g.y + 0.5f * ghr;
            const float gw = fmaxf(gwr, 1.0f), gh = fmaxf(ghr, 1.0f);
            const float d0 = ((gcx - acx) / aw) / 0.1f;
            const float d1 = ((gcy - acy) / ah) / 0.1f;
            const float d2 = __logf(gw / aw) / 0.2f;
            const float d3 = __logf(gh / ah) / 0.2f;
            const float4 pl = reinterpret_cast<const float4*>(loc)[(size_t)b * A + a];
            const float df[4] = { fabsf(d0 - pl.x), fabsf(d1 - pl.y),
                                  fabsf(d2 - pl.z), fabsf(d3 - pl.w) };
#pragma unroll
            for (int i = 0; i < 4; ++i) {
                const float d = df[i];
                loc_part += (d <= (1.0f / 9.0f)) ? (0.5f * 9.0f) * d * d
                                                 : d - (0.5f / 9.0f);
            }
        }
    } else if (t < ANCH) {
        s_status[t] = 255;
    }
    __syncthreads();

    // ---- Phase 2: 5-batch, 2-deep ping-pong pipeline (8 loads in flight) ----
    float cls_part = 0.0f;
    if (full) {
        EVALB(va, 0); LOADB(va, 2);
        EVALB(vb, 1); LOADB(vb, 3);
        EVALB(va, 2); LOADB(va, 4);
        EVALB(vb, 3);
        EVALB(va, 4);
    } else {
        const int total = nA * KQ;
        for (int idx = t; idx < total; idx += BLK) {
            const float4 v = cls4[idx];
            const int al = idx / KQ;
            const int c0 = (idx - al * KQ) * 4;
            quad(v, s_status[al], c0, cls_part);
        }
    }

    // ---- reduce within block, write per-block partials ----
#pragma unroll
    for (int off = 32; off > 0; off >>= 1) {
        cls_part += __shfl_down(cls_part, off);
        loc_part += __shfl_down(loc_part, off);
        pos_part += __shfl_down(pos_part, off);
    }
    const int wid = t >> 6;
    if ((t & 63) == 0) {
        s_redc[wid] = cls_part;
        s_redl[wid] = loc_part;
        s_redp[wid] = pos_part;
    }
    __syncthreads();
    const unsigned int nblk = (unsigned int)(B * NBX);
    if (t == 0) {
        float c = 0.0f, l = 0.0f, p = 0.0f;
#pragma unroll
        for (int w = 0; w < BLK / 64; ++w) { c += s_redc[w]; l += s_redl[w]; p += s_redp[w]; }
        part[(size_t)b * NBX + bx]           = c;
        part[(size_t)(B + b) * NBX + bx]     = l;
        part[(size_t)(2 * B + b) * NBX + bx] = p;
        __threadfence();                          // release partials (device scope)
        const unsigned int old = atomicAdd(counter, 1u);
        s_islast = (old == nblk - 1u) ? 1 : 0;    // counter zeroed per call
    }
    __syncthreads();

    // ---- true last-arriving block: final reduction (replaces 2nd kernel) ----
    if (s_islast) {
        __threadfence();                          // acquire other blocks' partials
        __shared__ float f_c[64], f_l[64];
        const int lane = t & 31;
        const int ngrp = BLK >> 5;
        if (t < 64) { f_c[t] = 0.0f; f_l[t] = 0.0f; }
        __syncthreads();
        for (int img = t >> 5; img < B; img += ngrp) {
            float c = 0.0f, l = 0.0f, p = 0.0f, nv = 0.0f;
            const float* pc = part + (size_t)img * NBX;
            const float* pl = part + (size_t)(B + img) * NBX;
            const float* pp = part + (size_t)(2 * B + img) * NBX;
            for (int e = lane; e < NBX; e += 32) { c += pc[e]; l += pl[e]; p += pp[e]; }
            for (int m = lane; m < M; m += 32)
                nv += (anno[((size_t)img * M + m) * 5 + 4] != -1.0f) ? 1.0f : 0.0f;
#pragma unroll
            for (int off = 16; off > 0; off >>= 1) {
                c  += __shfl_down(c,  off, 32);
                l  += __shfl_down(l,  off, 32);
                p  += __shfl_down(p,  off, 32);
                nv += __shfl_down(nv, off, 32);
            }
            if (lane == 0) {
                float cls_l = c / fmaxf(p, 1.0f);
                float loc_l = (p > 0.0f) ? l / fmaxf(4.0f * p, 1.0f) : 0.0f;
                if (nv == 0.0f) { cls_l = 0.0f; loc_l = 0.0f; }
                f_c[img] = cls_l;
                f_l[img] = loc_l;
            }
        }
        __syncthreads();
        if (t == 0) {
            float cs = 0.0f, ls = 0.0f;
            for (int i = 0; i < B; ++i) { cs += f_c[i]; ls += f_l[i]; }
            out[0] = cs / (float)B;
            out[1] = ls / (float)B;
        }
    }
#undef LOADB
#undef EVALB
}

extern "C" void kernel_launch(void* const* d_in, const int* in_sizes, int n_in,
                              void* d_out, int out_size, void* d_ws, size_t ws_size,
                              hipStream_t stream) {
    const float* cls     = (const float*)d_in[0];
    const float* loc     = (const float*)d_in[1];
    const float* anchors = (const float*)d_in[2];
    const float* anno    = (const float*)d_in[3];

    const int A  = in_sizes[2] / 4;
    const long long BA = (long long)in_sizes[1] / 4;   // B*A
    const int B  = (int)(BA / A);
    const int K  = (int)((long long)in_sizes[0] / BA);
    const int M  = in_sizes[3] / (B * 5);
    const int KQ = K >> 2;
    const int NBX = (A + ANCH - 1) / ANCH;

    float* part = (float*)d_ws;  // [3][B][NBX], every slot written each call
    unsigned int* counter = (unsigned int*)(part + (size_t)3 * B * NBX);

    // Counter MUST start at 0 every call (poison-proof; cheapest dispatch).
    hipMemsetAsync(counter, 0, sizeof(unsigned int), stream);

    dim3 grid(NBX, B);
    if (KQ == 20 && M == 32) {
        focal_main<20, 32><<<grid, BLK, 0, stream>>>(cls, loc, anchors, anno,
                                                     A, KQ, M, B, NBX, part,
                                                     counter, (float*)d_out);
    } else {
        focal_main<0, 0><<<grid, BLK, 0, stream>>>(cls, loc, anchors, anno,
                                                   A, KQ, M, B, NBX, part,
                                                   counter, (float*)d_out);
    }
}

// Round 9
// 58.425 us; speedup vs baseline: 2.9548x; 2.9548x over previous
//
#include <hip/hip_runtime.h>

#define BLK 256
#define ANCH 256
#define MAXM 64  // M=32 here; slack

constexpr float LN2 = 0.6931471805599453f;

// Background focal partial for one float4:  sum_i p_i^2 * log2(1 - p_i)   (<= 0)
__device__ __forceinline__ float bg4(const float4 v) {
    const float pv[4] = { v.x, v.y, v.z, v.w };
    float acc = 0.0f;
#pragma unroll
    for (int i = 0; i < 4; ++i) {
        const float p = fminf(fmaxf(pv[i], 0.0001f), 1.0f - 0.0001f);
        acc = fmaf(p * p, __log2f(1.0f - p), acc);
    }
    return acc;
}

// One quad (4 consecutive classes c0..c0+3) of one anchor with status st.
// st: 0..K-1 = positive label, 254 = negative, 255 = ignore.
__device__ __forceinline__ void quad(const float4 v, const int st, const int c0,
                                     float& cls_part) {
    const float s = bg4(v);
    cls_part = fmaf(s, (st == 255) ? 0.0f : -0.75f * LN2, cls_part);
    const unsigned d = (unsigned)(st - c0);
    if (d < 4u) {                       // rare: this quad holds the positive class
        float p = v.x;
        p = (d == 1) ? v.y : p;
        p = (d == 2) ? v.z : p;
        p = (d == 3) ? v.w : p;
        p = fminf(fmaxf(p, 0.0001f), 1.0f - 0.0001f);
        const float bg = p * p * __log2f(1.0f - p);
        const float q  = 1.0f - p;
        const float fg = q * q * __log2f(p);
        cls_part += -LN2 * (0.25f * fg - 0.75f * bg);   // add fg-term, remove bg-term
    }
}

template <int KQ_C, int M_C>
__global__ __launch_bounds__(BLK) void focal_main(
    const float* __restrict__ cls,
    const float* __restrict__ loc,
    const float* __restrict__ anchors,
    const float* __restrict__ anno,
    int A, int kq_dyn, int m_dyn, int B, int NBX,
    float* __restrict__ part)          // [3][B][NBX] partials, no atomics
{
    const int KQ = KQ_C ? KQ_C : kq_dyn;
    const int M  = M_C  ? M_C  : m_dyn;
    const int b  = blockIdx.y;
    const int bx = blockIdx.x;
    const int a0 = bx * ANCH;
    const int t  = threadIdx.x;
    const int nA = min(ANCH, A - a0);

    __shared__ float4 s_box[MAXM];
    __shared__ float  s_lab[MAXM];
    __shared__ int    s_status[ANCH];
    __shared__ float  s_redc[BLK / 64];
    __shared__ float  s_redl[BLK / 64];
    __shared__ float  s_redp[BLK / 64];

    const float4* __restrict__ cls4 =
        reinterpret_cast<const float4*>(cls) + ((size_t)b * A + a0) * KQ;
    const bool full = (KQ_C == 20) && (nA == ANCH);

    // ---- stage annotations FIRST, so the barrier drains only these loads
    //      and the cls preloads issued after it overlap phase-1 compute ----
    if (t < M) {
        const float* ap = anno + ((size_t)b * M + t) * 5;
        s_box[t] = make_float4(ap[0], ap[1], ap[2], ap[3]);
        s_lab[t] = ap[4];
    }
    __syncthreads();

#define LOADB(R, BK)                                                        \
    do {                                                                    \
        _Pragma("unroll") for (int u_ = 0; u_ < 4; ++u_)                    \
            R[u_] = cls4[t + ((BK) * 4 + u_) * BLK];                        \
    } while (0)

#define EVALB(R, BK)                                                        \
    do {                                                                    \
        _Pragma("unroll") for (int u_ = 0; u_ < 4; ++u_) {                  \
            const int idx_ = t + ((BK) * 4 + u_) * BLK;                     \
            const int al_  = idx_ / 20;                                     \
            const int c0_  = (idx_ - al_ * 20) * 4;                         \
            quad(R[u_], s_status[al_], c0_, cls_part);                      \
        }                                                                   \
    } while (0)

    // ---- 8 cls preloads in flight; phase-1 compute below hides them ----
    float4 va[4], vb[4];
    if (full) { LOADB(va, 0); LOADB(vb, 1); }

    float loc_part = 0.0f;
    float pos_part = 0.0f;

    // ---- Phase 1: per-anchor status + loc loss ----
    if (t < nA) {
        const int a = a0 + t;
        const float4 anc = reinterpret_cast<const float4*>(anchors)[a];
        const float ax1 = anc.x, ay1 = anc.y, ax2 = anc.z, ay2 = anc.w;
        const float area_a = (ax2 - ax1) * (ay2 - ay1);

        float best = -1e30f;
        int arg = 0;
#pragma unroll
        for (int m = 0; m < M; ++m) {
            const float4 bb = s_box[m];
            const float lb  = s_lab[m];
            float iou;
            if (lb != -1.0f) {
                const float area_b = (bb.z - bb.x) * (bb.w - bb.y);
                const float iw = fmaxf(fminf(ax2, bb.z) - fmaxf(ax1, bb.x), 0.0f);
                const float ih = fmaxf(fminf(ay2, bb.w) - fmaxf(ay1, bb.y), 0.0f);
                const float inter = iw * ih;
                const float uni = fmaxf(area_a + area_b - inter, 1e-8f);
                iou = inter / uni;
            } else {
                iou = -1.0f;
            }
            if (iou > best) { best = iou; arg = m; }  // strict > == jnp first-max
        }

        const bool pos = best >= 0.5f;
        const bool neg = best < 0.4f;
        s_status[t] = pos ? (int)s_lab[arg] : (neg ? 254 : 255);

        if (pos) {
            pos_part = 1.0f;
            const float4 g = s_box[arg];
            const float aw = ax2 - ax1, ah = ay2 - ay1;
            const float acx = ax1 + 0.5f * aw, acy = ay1 + 0.5f * ah;
            const float gwr = g.z - g.x, ghr = g.w - g.y;
            const float gcx = g.x + 0.5f * gwr, gcy = g.y + 0.5f * ghr;
            const float gw = fmaxf(gwr, 1.0f), gh = fmaxf(ghr, 1.0f);
            const float d0 = ((gcx - acx) / aw) / 0.1f;
            const float d1 = ((gcy - acy) / ah) / 0.1f;
            const float d2 = __logf(gw / aw) / 0.2f;
            const float d3 = __logf(gh / ah) / 0.2f;
            const float4 pl = reinterpret_cast<const float4*>(loc)[(size_t)b * A + a];
            const float df[4] = { fabsf(d0 - pl.x), fabsf(d1 - pl.y),
                                  fabsf(d2 - pl.z), fabsf(d3 - pl.w) };
#pragma unroll
            for (int i = 0; i < 4; ++i) {
                const float d = df[i];
                loc_part += (d <= (1.0f / 9.0f)) ? (0.5f * 9.0f) * d * d
                                                 : d - (0.5f / 9.0f);
            }
        }
    } else if (t < ANCH) {
        s_status[t] = 255;
    }
    __syncthreads();

    // ---- Phase 2: 5-batch, 2-deep ping-pong pipeline (8 loads in flight) ----
    float cls_part = 0.0f;
    if (full) {
        EVALB(va, 0); LOADB(va, 2);
        EVALB(vb, 1); LOADB(vb, 3);
        EVALB(va, 2); LOADB(va, 4);
        EVALB(vb, 3);
        EVALB(va, 4);
    } else {
        const int total = nA * KQ;
        for (int idx = t; idx < total; idx += BLK) {
            const float4 v = cls4[idx];
            const int al = idx / KQ;
            const int c0 = (idx - al * KQ) * 4;
            quad(v, s_status[al], c0, cls_part);
        }
    }

    // ---- reduce within block, write per-block partials (NO atomics) ----
#pragma unroll
    for (int off = 32; off > 0; off >>= 1) {
        cls_part += __shfl_down(cls_part, off);
        loc_part += __shfl_down(loc_part, off);
        pos_part += __shfl_down(pos_part, off);
    }
    const int wid = t >> 6;
    if ((t & 63) == 0) {
        s_redc[wid] = cls_part;
        s_redl[wid] = loc_part;
        s_redp[wid] = pos_part;
    }
    __syncthreads();
    if (t == 0) {
        float c = 0.0f, l = 0.0f, p = 0.0f;
#pragma unroll
        for (int w = 0; w < BLK / 64; ++w) { c += s_redc[w]; l += s_redl[w]; p += s_redp[w]; }
        part[(size_t)b * NBX + bx]           = c;
        part[(size_t)(B + b) * NBX + bx]     = l;
        part[(size_t)(2 * B + b) * NBX + bx] = p;
    }
#undef LOADB
#undef EVALB
}

// One 64-lane wave per image: halves the serial gather depth vs 32-lane groups.
__global__ __launch_bounds__(512) void focal_final(
    const float* __restrict__ anno, int B, int M, int NBX,
    const float* __restrict__ part, float* __restrict__ out)
{
    __shared__ float s_c[64], s_l[64];
    const int t = threadIdx.x;
    const int lane = t & 63;
    const int wid  = t >> 6;
    const int nwv  = (int)blockDim.x >> 6;
    if (t < 64) { s_c[t] = 0.0f; s_l[t] = 0.0f; }
    __syncthreads();

    for (int img = wid; img < B; img += nwv) {
        float c = 0.0f, l = 0.0f, p = 0.0f, nv = 0.0f;
        const float* pc = part + (size_t)img * NBX;
        const float* pl = part + (size_t)(B + img) * NBX;
        const float* pp = part + (size_t)(2 * B + img) * NBX;
        for (int e = lane; e < NBX; e += 64) { c += pc[e]; l += pl[e]; p += pp[e]; }
        for (int m = lane; m < M; m += 64)
            nv += (anno[((size_t)img * M + m) * 5 + 4] != -1.0f) ? 1.0f : 0.0f;
#pragma unroll
        for (int off = 32; off > 0; off >>= 1) {
            c  += __shfl_down(c,  off);
            l  += __shfl_down(l,  off);
            p  += __shfl_down(p,  off);
            nv += __shfl_down(nv, off);
        }
        if (lane == 0) {
            float cls_l = c / fmaxf(p, 1.0f);
            float loc_l = (p > 0.0f) ? l / fmaxf(4.0f * p, 1.0f) : 0.0f;
            if (nv == 0.0f) { cls_l = 0.0f; loc_l = 0.0f; }
            s_c[img] = cls_l;
            s_l[img] = loc_l;
        }
    }
    __syncthreads();
    if (t == 0) {
        float cs = 0.0f, ls = 0.0f;
        for (int i = 0; i < B; ++i) { cs += s_c[i]; ls += s_l[i]; }
        out[0] = cs / (float)B;
        out[1] = ls / (float)B;
    }
}

extern "C" void kernel_launch(void* const* d_in, const int* in_sizes, int n_in,
                              void* d_out, int out_size, void* d_ws, size_t ws_size,
                              hipStream_t stream) {
    const float* cls     = (const float*)d_in[0];
    const float* loc     = (const float*)d_in[1];
    const float* anchors = (const float*)d_in[2];
    const float* anno    = (const float*)d_in[3];

    const int A  = in_sizes[2] / 4;
    const long long BA = (long long)in_sizes[1] / 4;   // B*A
    const int B  = (int)(BA / A);
    const int K  = (int)((long long)in_sizes[0] / BA);
    const int M  = in_sizes[3] / (B * 5);
    const int KQ = K >> 2;
    const int NBX = (A + ANCH - 1) / ANCH;

    float* part = (float*)d_ws;  // [3][B][NBX], every slot written each call

    dim3 grid(NBX, B);
    if (KQ == 20 && M == 32) {
        focal_main<20, 32><<<grid, BLK, 0, stream>>>(cls, loc, anchors, anno,
                                                     A, KQ, M, B, NBX, part);
    } else {
        focal_main<0, 0><<<grid, BLK, 0, stream>>>(cls, loc, anchors, anno,
                                                   A, KQ, M, B, NBX, part);
    }
    focal_final<<<1, 512, 0, stream>>>(anno, B, M, NBX, part, (float*)d_out);
}

// Round 10
// 55.474 us; speedup vs baseline: 3.1120x; 1.0532x over previous
//
#include <hip/hip_runtime.h>

#define BLK 256
#define ANCH 256
#define MAXM 64  // M=32 here; slack

constexpr float LN2 = 0.6931471805599453f;

// Background focal partial for one float4:  sum_i p_i^2 * log2(1 - p_i)   (<= 0)
__device__ __forceinline__ float bg4(const float4 v) {
    const float pv[4] = { v.x, v.y, v.z, v.w };
    float acc = 0.0f;
#pragma unroll
    for (int i = 0; i < 4; ++i) {
        const float p = fminf(fmaxf(pv[i], 0.0001f), 1.0f - 0.0001f);
        acc = fmaf(p * p, __log2f(1.0f - p), acc);
    }
    return acc;
}

// One quad (4 consecutive classes c0..c0+3) of one anchor with status st.
// st: 0..K-1 = positive label, 254 = negative, 255 = ignore.
__device__ __forceinline__ void quad(const float4 v, const int st, const int c0,
                                     float& cls_part) {
    const float s = bg4(v);
    cls_part = fmaf(s, (st == 255) ? 0.0f : -0.75f * LN2, cls_part);
    const unsigned d = (unsigned)(st - c0);
    if (d < 4u) {                       // rare: this quad holds the positive class
        float p = v.x;
        p = (d == 1) ? v.y : p;
        p = (d == 2) ? v.z : p;
        p = (d == 3) ? v.w : p;
        p = fminf(fmaxf(p, 0.0001f), 1.0f - 0.0001f);
        const float bg = p * p * __log2f(1.0f - p);
        const float q  = 1.0f - p;
        const float fg = q * q * __log2f(p);
        cls_part += -LN2 * (0.25f * fg - 0.75f * bg);   // add fg-term, remove bg-term
    }
}

template <int KQ_C, int M_C>
__global__ __launch_bounds__(BLK) void focal_main(
    const float* __restrict__ cls,
    const float* __restrict__ loc,
    const float* __restrict__ anchors,
    const float* __restrict__ anno,
    int A, int kq_dyn, int m_dyn, int B, int NBX,
    float* __restrict__ part)          // [3][B][NBX] partials, no atomics
{
    const int KQ = KQ_C ? KQ_C : kq_dyn;
    const int M  = M_C  ? M_C  : m_dyn;
    const int b  = blockIdx.y;
    const int bx = blockIdx.x;
    const int a0 = bx * ANCH;
    const int t  = threadIdx.x;
    const int nA = min(ANCH, A - a0);

    __shared__ float4 s_box[MAXM];
    __shared__ float  s_lab[MAXM];
    __shared__ int    s_status[ANCH];
    __shared__ float  s_redc[BLK / 64];
    __shared__ float  s_redl[BLK / 64];
    __shared__ float  s_redp[BLK / 64];

    const float4* __restrict__ cls4 =
        reinterpret_cast<const float4*>(cls) + ((size_t)b * A + a0) * KQ;
    // clamp for safe single-path loads in the (rare) partial block
    const int qcap = nA * KQ - 1;

    // ---- stage annotations + hoist this thread's anchor above the barrier
    //      (the barrier drain covers both; cls preloads issued after it) ----
    if (t < M) {
        const float* ap = anno + ((size_t)b * M + t) * 5;
        s_box[t] = make_float4(ap[0], ap[1], ap[2], ap[3]);
        s_lab[t] = ap[4];
    }
    const float4 anc =
        reinterpret_cast<const float4*>(anchors)[a0 + min(t, nA - 1)];
    __syncthreads();

#define LOADB(R, BK)                                                        \
    do {                                                                    \
        _Pragma("unroll") for (int u_ = 0; u_ < 4; ++u_)                    \
            R[u_] = cls4[min(t + ((BK) * 4 + u_) * BLK, qcap)];             \
    } while (0)

#define EVALB(R, BK)                                                        \
    do {                                                                    \
        _Pragma("unroll") for (int u_ = 0; u_ < 4; ++u_) {                  \
            const int idx_ = t + ((BK) * 4 + u_) * BLK;                     \
            const int al_  = idx_ / 20;     /* unclamped: OOB -> status 255 */ \
            const int c0_  = (idx_ - al_ * 20) * 4;                         \
            quad(R[u_], s_status[al_], c0_, cls_part);                      \
        }                                                                   \
    } while (0)

    // ---- 8 cls preloads in flight; phase-1 compute below hides them ----
    float4 va[4], vb[4];
    if constexpr (KQ_C == 20) { LOADB(va, 0); LOADB(vb, 1); }

    float loc_part = 0.0f;
    float pos_part = 0.0f;

    // ---- Phase 1: per-anchor status + loc loss ----
    if (t < nA) {
        const int a = a0 + t;
        const float ax1 = anc.x, ay1 = anc.y, ax2 = anc.z, ay2 = anc.w;
        const float area_a = (ax2 - ax1) * (ay2 - ay1);

        float best = -1e30f;
        int arg = 0;
#pragma unroll
        for (int m = 0; m < M; ++m) {
            const float4 bb = s_box[m];
            const float lb  = s_lab[m];
            float iou;
            if (lb != -1.0f) {
                const float area_b = (bb.z - bb.x) * (bb.w - bb.y);
                const float iw = fmaxf(fminf(ax2, bb.z) - fmaxf(ax1, bb.x), 0.0f);
                const float ih = fmaxf(fminf(ay2, bb.w) - fmaxf(ay1, bb.y), 0.0f);
                const float inter = iw * ih;
                const float uni = fmaxf(area_a + area_b - inter, 1e-8f);
                iou = inter / uni;
            } else {
                iou = -1.0f;
            }
            if (iou > best) { best = iou; arg = m; }  // strict > == jnp first-max
        }

        const bool pos = best >= 0.5f;
        const bool neg = best < 0.4f;
        s_status[t] = pos ? (int)s_lab[arg] : (neg ? 254 : 255);

        if (pos) {
            pos_part = 1.0f;
            const float4 g = s_box[arg];
            const float aw = ax2 - ax1, ah = ay2 - ay1;
            const float acx = ax1 + 0.5f * aw, acy = ay1 + 0.5f * ah;
            const float gwr = g.z - g.x, ghr = g.w - g.y;
            const float gcx = g.x + 0.5f * gwr, gcy = g.y + 0.5f * ghr;
            const float gw = fmaxf(gwr, 1.0f), gh = fmaxf(ghr, 1.0f);
            const float d0 = ((gcx - acx) / aw) / 0.1f;
            const float d1 = ((gcy - acy) / ah) / 0.1f;
            const float d2 = __logf(gw / aw) / 0.2f;
            const float d3 = __logf(gh / ah) / 0.2f;
            const float4 pl = reinterpret_cast<const float4*>(loc)[(size_t)b * A + a];
            const float df[4] = { fabsf(d0 - pl.x), fabsf(d1 - pl.y),
                                  fabsf(d2 - pl.z), fabsf(d3 - pl.w) };
#pragma unroll
            for (int i = 0; i < 4; ++i) {
                const float d = df[i];
                loc_part += (d <= (1.0f / 9.0f)) ? (0.5f * 9.0f) * d * d
                                                 : d - (0.5f / 9.0f);
            }
        }
    } else {
        s_status[t] = 255;
    }
    __syncthreads();

    // ---- Phase 2: single-path 5-batch 2-deep pipeline (8 loads in flight) ----
    float cls_part = 0.0f;
    if constexpr (KQ_C == 20) {
        EVALB(va, 0); LOADB(va, 2);
        EVALB(vb, 1); LOADB(vb, 3);
        EVALB(va, 2); LOADB(va, 4);
        EVALB(vb, 3);
        EVALB(va, 4);
    } else {
        const int total = nA * KQ;
        for (int idx = t; idx < total; idx += BLK) {
            const float4 v = cls4[idx];
            const int al = idx / KQ;
            const int c0 = (idx - al * KQ) * 4;
            quad(v, s_status[al], c0, cls_part);
        }
    }

    // ---- reduce within block, write per-block partials (NO atomics) ----
#pragma unroll
    for (int off = 32; off > 0; off >>= 1) {
        cls_part += __shfl_down(cls_part, off);
        loc_part += __shfl_down(loc_part, off);
        pos_part += __shfl_down(pos_part, off);
    }
    const int wid = t >> 6;
    if ((t & 63) == 0) {
        s_redc[wid] = cls_part;
        s_redl[wid] = loc_part;
        s_redp[wid] = pos_part;
    }
    __syncthreads();
    if (t == 0) {
        float c = 0.0f, l = 0.0f, p = 0.0f;
#pragma unroll
        for (int w = 0; w < BLK / 64; ++w) { c += s_redc[w]; l += s_redl[w]; p += s_redp[w]; }
        part[(size_t)b * NBX + bx]           = c;
        part[(size_t)(B + b) * NBX + bx]     = l;
        part[(size_t)(2 * B + b) * NBX + bx] = p;
    }
#undef LOADB
#undef EVALB
}

// One 64-lane wave per image.
__global__ __launch_bounds__(512) void focal_final(
    const float* __restrict__ anno, int B, int M, int NBX,
    const float* __restrict__ part, float* __restrict__ out)
{
    __shared__ float s_c[64], s_l[64];
    const int t = threadIdx.x;
    const int lane = t & 63;
    const int wid  = t >> 6;
    const int nwv  = (int)blockDim.x >> 6;
    if (t < 64) { s_c[t] = 0.0f; s_l[t] = 0.0f; }
    __syncthreads();

    for (int img = wid; img < B; img += nwv) {
        float c = 0.0f, l = 0.0f, p = 0.0f, nv = 0.0f;
        const float* pc = part + (size_t)img * NBX;
        const float* pl = part + (size_t)(B + img) * NBX;
        const float* pp = part + (size_t)(2 * B + img) * NBX;
        for (int e = lane; e < NBX; e += 64) { c += pc[e]; l += pl[e]; p += pp[e]; }
        for (int m = lane; m < M; m += 64)
            nv += (anno[((size_t)img * M + m) * 5 + 4] != -1.0f) ? 1.0f : 0.0f;
#pragma unroll
        for (int off = 32; off > 0; off >>= 1) {
            c  += __shfl_down(c,  off);
            l  += __shfl_down(l,  off);
            p  += __shfl_down(p,  off);
            nv += __shfl_down(nv, off);
        }
        if (lane == 0) {
            float cls_l = c / fmaxf(p, 1.0f);
            float loc_l = (p > 0.0f) ? l / fmaxf(4.0f * p, 1.0f) : 0.0f;
            if (nv == 0.0f) { cls_l = 0.0f; loc_l = 0.0f; }
            s_c[img] = cls_l;
            s_l[img] = loc_l;
        }
    }
    __syncthreads();
    if (t == 0) {
        float cs = 0.0f, ls = 0.0f;
        for (int i = 0; i < B; ++i) { cs += s_c[i]; ls += s_l[i]; }
        out[0] = cs / (float)B;
        out[1] = ls / (float)B;
    }
}

extern "C" void kernel_launch(void* const* d_in, const int* in_sizes, int n_in,
                              void* d_out, int out_size, void* d_ws, size_t ws_size,
                              hipStream_t stream) {
    const float* cls     = (const float*)d_in[0];
    const float* loc     = (const float*)d_in[1];
    const float* anchors = (const float*)d_in[2];
    const float* anno    = (const float*)d_in[3];

    const int A  = in_sizes[2] / 4;
    const long long BA = (long long)in_sizes[1] / 4;   // B*A
    const int B  = (int)(BA / A);
    const int K  = (int)((long long)in_sizes[0] / BA);
    const int M  = in_sizes[3] / (B * 5);
    const int KQ = K >> 2;
    const int NBX = (A + ANCH - 1) / ANCH;

    float* part = (float*)d_ws;  // [3][B][NBX], every slot written each call

    dim3 grid(NBX, B);
    if (KQ == 20 && M == 32) {
        focal_main<20, 32><<<grid, BLK, 0, stream>>>(cls, loc, anchors, anno,
                                                     A, KQ, M, B, NBX, part);
    } else {
        focal_main<0, 0><<<grid, BLK, 0, stream>>>(cls, loc, anchors, anno,
                                                   A, KQ, M, B, NBX, part);
    }
    focal_final<<<1, 512, 0, stream>>>(anno, B, M, NBX, part, (float*)d_out);
}